// Round 5
// baseline (6251.755 us; speedup 1.0000x reference)
//
#include <hip/hip_runtime.h>

#define DEV __device__ __forceinline__

#define Dd   64
#define Bb   1024
#define Mm   32
#define Kk   16
#define Ll   8
#define NKGk 65536
#define NH   32768            // B*M
#define ROWS (NH + 2*Bb)      // 34816

// ---- workspace layout (float offsets) ----
#define OFF_WTATT   0          // 64x64  transposed W_tatt
#define OFF_WGS     4096       // 64x64  transposed W_gatt[:, :64]   (WgsT[j*64+d] = W_gatt[d][j])
#define OFF_WCOMB   8192       // 128x64 transposed (W_gatt[:,64:] @ W_re)
#define OFF_WRE     16384      // 128x64 transposed W_re
#define OFF_WAGG    24576      // 128x64 transposed W_agg (WaggT[j*64+d] = W_agg[d][j], j<128)
#define OFF_WU      32768      // 192x64 transposed W_u_mlp
#define OFF_GVEC    45056      // 64     sigmoid(gate)
#define OFF_USERG   45120      // 1024x64
#define OFF_UATT    110656     // 1024x64
#define OFF_SELFH   176192     // 32768x64
#define OFF_HISLC   2273344    // 32768x64
#define OFF_HISGB   4370496    // 32768x64
#define OFF_SELFPN  6467648    // 2x1024x64 (pos, then neg)
#define OFF_LCPN    6598720    // 2x1024x64
#define OFF_GBPN    6729792    // 2x1024x64
#define OFF_ULCPN   6860864    // 2x1024x128
#define OFF_KGSUM   7123008    // 1
#define OFF_KGS     7123012    // 2x65536 kg squared distances (pos, neg)

DEV float4 ld4(const float* p){ return *reinterpret_cast<const float4*>(p); }
DEV void st4(float* p, const float4 v){ *reinterpret_cast<float4*>(p) = v; }

DEV float tanh_fast(float x){
  float cx = fminf(15.f, fmaxf(-15.f, x));
  float e = __expf(2.f*cx);
  return __fdividef(e - 1.f, e + 1.f);
}
DEV float sigmoid_fast(float x){ return __fdividef(1.f, 1.f + __expf(-x)); }

// acc[d] += W^T rows (4 consecutive) dotted against a float4 of x.
// W_ points at 256 contiguous floats (4 rows x 64) -> wave-uniform s_loads.
// NOTE: macro params must not collide with .x/.y/.z/.w member tokens.
#define MV4(ACC_, W_, X4_) \
  { _Pragma("unroll") for (int d_ = 0; d_ < 64; ++d_) ACC_[d_] += (W_)[d_]       * (X4_).x; \
    _Pragma("unroll") for (int d_ = 0; d_ < 64; ++d_) ACC_[d_] += (W_)[64 + d_]  * (X4_).y; \
    _Pragma("unroll") for (int d_ = 0; d_ < 64; ++d_) ACC_[d_] += (W_)[128 + d_] * (X4_).z; \
    _Pragma("unroll") for (int d_ = 0; d_ < 64; ++d_) ACC_[d_] += (W_)[192 + d_] * (X4_).w; }

// ---------------- prep: weight transposes, Wcomb fold, gate sigmoid ----------------
__global__ void prep_kernel(const float* __restrict__ W_tatt, const float* __restrict__ W_gatt,
                            const float* __restrict__ W_re, const float* __restrict__ W_agg,
                            const float* __restrict__ W_u, const float* __restrict__ gate,
                            float* __restrict__ ws)
{
  int t = threadIdx.x;
  for (int i = t; i < 4096; i += 256){
    int d = i >> 6, j = i & 63;
    ws[OFF_WTATT + j*64 + d] = W_tatt[i];            // W_tatt (64,64)
    ws[OFF_WGS   + j*64 + d] = W_gatt[d*128 + j];    // self half of W_gatt
  }
  for (int i = t; i < 8192; i += 256){
    int j = i >> 6, d = i & 63;
    ws[OFF_WRE  + i] = W_re[d*128 + j];
    ws[OFF_WAGG + i] = W_agg[d*128 + j];
    float s = 0.f;
    for (int dp = 0; dp < 64; ++dp) s += W_gatt[d*128 + 64 + dp] * W_re[dp*128 + j];
    ws[OFF_WCOMB + i] = s;                           // (W_gatt[:,64:] @ W_re)^T
  }
  for (int i = t; i < 12288; i += 256){
    int j = i >> 6, d = i & 63;
    ws[OFF_WU + i] = W_u[d*192 + j];
  }
  if (t < 64) ws[OFF_GVEC + t] = sigmoid_fast(gate[t]);
}

// ---------------- user gather + u_att = relu(user_g @ W_tatt^T + b_tatt) ----------------
__global__ void user_prep_kernel(const int* __restrict__ uidx, const float* __restrict__ user_emb,
                                 const float* __restrict__ b_tatt, float* __restrict__ ws)
{
  int gid = blockIdx.x*256 + threadIdx.x;
  int b = gid >> 6, lane = gid & 63;
  long ui = uidx[b];
  float ugd = user_emb[ui*64 + lane];
  ws[OFF_USERG + b*64 + lane] = ugd;
  const float* WtT = ws + OFF_WTATT;
  float acc = b_tatt[lane];
  for (int j = 0; j < 64; ++j) acc += WtT[j*64 + lane] * __shfl(ugd, j);
  ws[OFF_UATT + b*64 + lane] = fmaxf(acc, 0.f);
}

// ---------------- agg_lc v2: thread = (row, k); 16 rows x 16 k per block ----------------
__global__ __launch_bounds__(256) void agg2_kernel(
  const int* __restrict__ hS, const int* __restrict__ hN, const int* __restrict__ hR,
  const int* __restrict__ pS, const int* __restrict__ pN, const int* __restrict__ pR,
  const int* __restrict__ nS, const int* __restrict__ nN, const int* __restrict__ nR,
  const float* __restrict__ entity, const float* __restrict__ relation,
  const float* __restrict__ b_gatt, const float* __restrict__ b_agg,
  float* __restrict__ ws)
{
  int tid = threadIdx.x;
  int k = tid & 15, rl = tid >> 4;          // k-lane, row-in-block
  int rbase = blockIdx.x*16;
  const int *sI, *nI, *rI; float *sO, *aO; int nb0, uhis;
  if (rbase < NH)          { sI=hS; nI=hN; rI=hR; sO=ws+OFF_SELFH;        aO=ws+OFF_HISLC;       nb0=rbase;        uhis=1; }
  else if (rbase < NH+Bb)  { sI=pS; nI=pN; rI=pR; sO=ws+OFF_SELFPN;       aO=ws+OFF_LCPN;       nb0=rbase-NH;     uhis=0; }
  else                     { sI=nS; nI=nN; rI=nR; sO=ws+OFF_SELFPN+65536; aO=ws+OFF_LCPN+65536; nb0=rbase-NH-Bb;  uhis=0; }
  int n = nb0 + rl;
  int urow = uhis ? (n >> 5) : n;

  const float* es = entity + (long)sI[n]*64;
  // ---- sc part: lane owns outputs o = k*4 .. k*4+3 of  sc = b_gatt + Wg_self@self ----
  const float* WgsT = ws + OFF_WGS;
  float4 sc4 = ld4(b_gatt + k*4);
  for (int j4 = 0; j4 < 16; ++j4){
    float4 s4 = ld4(es + 4*j4);
    float4 w0 = ld4(WgsT + (4*j4+0)*64 + k*4);
    float4 w1 = ld4(WgsT + (4*j4+1)*64 + k*4);
    float4 w2 = ld4(WgsT + (4*j4+2)*64 + k*4);
    float4 w3 = ld4(WgsT + (4*j4+3)*64 + k*4);
    sc4.x += w0.x*s4.x + w1.x*s4.y + w2.x*s4.z + w3.x*s4.w;
    sc4.y += w0.y*s4.x + w1.y*s4.y + w2.y*s4.z + w3.y*s4.w;
    sc4.z += w0.z*s4.x + w1.z*s4.y + w2.z*s4.z + w3.z*s4.w;
    sc4.w += w0.w*s4.x + w1.w*s4.y + w2.w*s4.z + w3.w*s4.w;
  }
  // store self_v chunk (lane k stores dims k*4..k*4+3)
  st4(sO + (long)n*64 + k*4, ld4(es + k*4));

  // ---- neighbor matvec: acc = Wcomb @ [nbr | rel]  (wave-uniform s_load weights) ----
  long nbI = nI[n*16 + k], rlI = rI[n*16 + k];
  const float* en = entity + nbI*64;
  const float* er = relation + rlI*64;
  float xnb[64];
  #pragma unroll
  for (int j4 = 0; j4 < 16; ++j4){
    float4 x4 = ld4(en + 4*j4);
    xnb[4*j4+0] = x4.x; xnb[4*j4+1] = x4.y; xnb[4*j4+2] = x4.z; xnb[4*j4+3] = x4.w;
  }
  float acc[64];
  #pragma unroll
  for (int d = 0; d < 64; ++d) acc[d] = 0.f;
  const float* WcT = ws + OFF_WCOMB;
  for (int j4 = 0; j4 < 16; ++j4){
    float4 x4 = ld4(en + 4*j4);
    MV4(acc, WcT + j4*256, x4);
  }
  for (int j4 = 0; j4 < 16; ++j4){
    float4 x4 = ld4(er + 4*j4);
    MV4(acc, WcT + 4096 + j4*256, x4);
  }
  // ---- logit = u_att . tanh(sc + acc)  (sc broadcast from owner lanes) ----
  int gl = (tid & 63) & 48;                 // group base lane within wave
  const float* up = ws + OFF_UATT + (long)urow*64;
  float lg = 0.f;
  #pragma unroll
  for (int j4 = 0; j4 < 16; ++j4){
    float4 u4 = ld4(up + 4*j4);
    float s0 = __shfl(sc4.x, gl + j4);
    float s1 = __shfl(sc4.y, gl + j4);
    float s2 = __shfl(sc4.z, gl + j4);
    float s3 = __shfl(sc4.w, gl + j4);
    lg += u4.x*tanh_fast(acc[4*j4+0] + s0);
    lg += u4.y*tanh_fast(acc[4*j4+1] + s1);
    lg += u4.z*tanh_fast(acc[4*j4+2] + s2);
    lg += u4.w*tanh_fast(acc[4*j4+3] + s3);
  }
  // ---- softmax over the 16 k-lanes ----
  float mx = lg;
  mx = fmaxf(mx, __shfl_xor(mx, 1)); mx = fmaxf(mx, __shfl_xor(mx, 2));
  mx = fmaxf(mx, __shfl_xor(mx, 4)); mx = fmaxf(mx, __shfl_xor(mx, 8));
  float e = __expf(lg - mx);
  float se = e;
  se += __shfl_xor(se, 1); se += __shfl_xor(se, 2);
  se += __shfl_xor(se, 4); se += __shfl_xor(se, 8);
  float att = __fdividef(e, se);
  // ---- agg: lane computes outputs o = k*4..k*4+3 of tanh(W_agg@[self|new_v]+b) ----
  const float* WaT = ws + OFF_WAGG;
  float4 a4 = ld4(b_agg + k*4);
  for (int j4 = 0; j4 < 16; ++j4){          // self half (streamed, L1-hot)
    float4 s4 = ld4(es + 4*j4);
    float4 w0 = ld4(WaT + (4*j4+0)*64 + k*4);
    float4 w1 = ld4(WaT + (4*j4+1)*64 + k*4);
    float4 w2 = ld4(WaT + (4*j4+2)*64 + k*4);
    float4 w3 = ld4(WaT + (4*j4+3)*64 + k*4);
    a4.x += w0.x*s4.x + w1.x*s4.y + w2.x*s4.z + w3.x*s4.w;
    a4.y += w0.y*s4.x + w1.y*s4.y + w2.y*s4.z + w3.y*s4.w;
    a4.z += w0.z*s4.x + w1.z*s4.y + w2.z*s4.z + w3.z*s4.w;
    a4.w += w0.w*s4.x + w1.w*s4.y + w2.w*s4.z + w3.w*s4.w;
  }
  #pragma unroll
  for (int j = 0; j < 64; ++j){             // new_v half via 16-lane butterfly
    float v = att * xnb[j];
    v += __shfl_xor(v, 1); v += __shfl_xor(v, 2);
    v += __shfl_xor(v, 4); v += __shfl_xor(v, 8);
    float4 wv = ld4(WaT + (64+j)*64 + k*4);
    a4.x += wv.x*v; a4.y += wv.y*v; a4.z += wv.z*v; a4.w += wv.w*v;
  }
  float t0 = tanh_fast(a4.x), t1 = tanh_fast(a4.y), t2 = tanh_fast(a4.z), t3 = tanh_fast(a4.w);
  float ss = t0*t0 + t1*t1 + t2*t2 + t3*t3;
  ss += __shfl_xor(ss, 1); ss += __shfl_xor(ss, 2);
  ss += __shfl_xor(ss, 4); ss += __shfl_xor(ss, 8);
  float rn = __fdividef(1.f, fmaxf(sqrtf(ss), 1e-12f));
  float4 o4; o4.x = t0*rn; o4.y = t1*rn; o4.z = t2*rn; o4.w = t3*rn;
  st4(aO + (long)n*64 + k*4, o4);
}

// ---------------- GRU v3: block = 64 rows x 4 waves; wave w owns outputs [w*16,w*16+16) ----
// v3 fix: h_prev[o] read from LDS (was dynamic VGPR index -> 227 MB scratch spill)
__global__ __launch_bounds__(256, 3) void gru2_kernel(
  const int* __restrict__ hS, const int* __restrict__ hP,
  const int* __restrict__ pS, const int* __restrict__ pP,
  const int* __restrict__ nS, const int* __restrict__ nP,
  const float* __restrict__ entity,
  const float* __restrict__ W_ih, const float* __restrict__ W_hh,
  const float* __restrict__ b_ih, const float* __restrict__ b_hh,
  const float* __restrict__ W_agg, const float* __restrict__ b_agg,
  float* __restrict__ ws)
{
  __shared__ float hb[2][64][64];           // [buf][dim][row] double-buffered h
  int tid = threadIdx.x;
  int w = __builtin_amdgcn_readfirstlane(tid >> 6);
  int lane = tid & 63;
  int rbase = blockIdx.x*64;
  const int *sIv, *pIv; float* aO; int nb0;
  if (rbase < NH)          { sIv=hS; pIv=hP; aO=ws+OFF_HISGB;        nb0=rbase; }
  else if (rbase < NH+Bb)  { sIv=pS; pIv=pP; aO=ws+OFF_GBPN;        nb0=rbase-NH; }
  else                     { sIv=nS; pIv=nP; aO=ws+OFF_GBPN+65536;  nb0=rbase-NH-Bb; }
  int n = nb0 + lane;

  for (int i = tid; i < 4096; i += 256) ((float*)hb)[i] = 0.f;   // zero buffer 0
  int o0 = w*16;
  int pt = pIv[n*8];
  __syncthreads();

  for (int t = 0; t < 8; ++t){
    int ptn = (t < 7) ? pIv[n*8 + t + 1] : 0;
    const float* ex = entity + (long)pt*64;
    float x[64];
    #pragma unroll
    for (int j4 = 0; j4 < 16; ++j4){
      float4 v = ld4(ex + 4*j4);
      x[4*j4] = v.x; x[4*j4+1] = v.y; x[4*j4+2] = v.z; x[4*j4+3] = v.w;
    }
    int cur = t & 1, nxt = cur ^ 1;
    float hc[64];
    #pragma unroll
    for (int j = 0; j < 64; ++j) hc[j] = hb[cur][j][lane];
    for (int i = 0; i < 16; ++i){
      int o = o0 + i;
      float air = b_ih[o], aiz = b_ih[64+o], ain = b_ih[128+o];
      float ahr = b_hh[o], ahz = b_hh[64+o], ahn = b_hh[128+o];
      const float* wi0 = W_ih + o*64;  const float* wi1 = W_ih + (64+o)*64;  const float* wi2 = W_ih + (128+o)*64;
      const float* wh0 = W_hh + o*64;  const float* wh1 = W_hh + (64+o)*64;  const float* wh2 = W_hh + (128+o)*64;
      #pragma unroll
      for (int j = 0; j < 64; ++j){
        air += wi0[j]*x[j]; aiz += wi1[j]*x[j]; ain += wi2[j]*x[j];
        ahr += wh0[j]*hc[j]; ahz += wh1[j]*hc[j]; ahn += wh2[j]*hc[j];
      }
      float r  = sigmoid_fast(air + ahr);
      float z  = sigmoid_fast(aiz + ahz);
      float nn = tanh_fast(ain + r*ahn);
      float hprev = hb[cur][o][lane];          // LDS read, NOT dynamic reg index
      hb[nxt][o][lane] = (1.f - z)*nn + z*hprev;
    }
    pt = ptn;
    __syncthreads();
  }
  // final h in hb[0]. agg = normalize(tanh(W_agg@[self|hT]+b_agg))
  const float* es = entity + (long)sIv[n]*64;
  float sv[64];
  #pragma unroll
  for (int j4 = 0; j4 < 16; ++j4){
    float4 v = ld4(es + 4*j4);
    sv[4*j4] = v.x; sv[4*j4+1] = v.y; sv[4*j4+2] = v.z; sv[4*j4+3] = v.w;
  }
  float hT[64];
  #pragma unroll
  for (int j = 0; j < 64; ++j) hT[j] = hb[0][j][lane];
  __syncthreads();                                    // before reusing hb[1] as transpose buf
  for (int i = 0; i < 16; ++i){
    int o = o0 + i;
    float a = b_agg[o];
    const float* wr = W_agg + (long)o*128;
    #pragma unroll
    for (int j = 0; j < 64; ++j) a += wr[j]*sv[j];
    #pragma unroll
    for (int j = 0; j < 64; ++j) a += wr[64+j]*hT[j];
    hb[1][o][lane] = tanh_fast(a);
  }
  __syncthreads();
  // normalize + coalesced store: thread (q = tid&3, r = tid>>2)
  int q = tid & 3, r = tid >> 2;
  float vv[16];
  float ss = 0.f;
  #pragma unroll
  for (int jj = 0; jj < 16; ++jj){ float v = hb[1][q*16+jj][r]; vv[jj] = v; ss += v*v; }
  ss += __shfl_xor(ss, 1); ss += __shfl_xor(ss, 2);
  float rn = __fdividef(1.f, fmaxf(sqrtf(ss), 1e-12f));
  int n2 = nb0 + r;
  #pragma unroll
  for (int jj4 = 0; jj4 < 4; ++jj4){
    float4 o4; o4.x = vv[4*jj4]*rn; o4.y = vv[4*jj4+1]*rn; o4.z = vv[4*jj4+2]*rn; o4.w = vv[4*jj4+3]*rn;
    st4(aO + (long)n2*64 + q*16 + 4*jj4, o4);
  }
}

// ---------------- KG v2: thread = (r, branch); store squared distances ----------------
__global__ __launch_bounds__(256) void kg2_kernel(
  const int* __restrict__ kh, const int* __restrict__ kr,
  const int* __restrict__ kt, const int* __restrict__ ktn,
  const float* __restrict__ entity, const float* __restrict__ relation,
  float* __restrict__ ws)
{
  int tid = threadIdx.x;
  int br = blockIdx.x >> 8;
  int r  = (blockIdx.x & 255)*256 + tid;
  const int* tailI = br ? ktn : kt;
  const float* WreT = ws + OFF_WRE;
  const float* er = relation + (long)kr[r]*64;
  const float* et = entity + (long)tailI[r]*64;
  float acc[64];
  #pragma unroll
  for (int d = 0; d < 64; ++d) acc[d] = 0.f;
  for (int j4 = 0; j4 < 16; ++j4){
    float4 x4 = ld4(et + 4*j4);
    MV4(acc, WreT + j4*256, x4);
  }
  for (int j4 = 0; j4 < 16; ++j4){
    float4 x4 = ld4(er + 4*j4);
    MV4(acc, WreT + 4096 + j4*256, x4);
  }
  const float* eh = entity + (long)kh[r]*64;
  float s = 0.f;
  #pragma unroll
  for (int j4 = 0; j4 < 16; ++j4){
    float4 h4 = ld4(eh + 4*j4);
    float d0 = h4.x - acc[4*j4+0], d1 = h4.y - acc[4*j4+1];
    float d2 = h4.z - acc[4*j4+2], d3 = h4.w - acc[4*j4+3];
    s += d0*d0 + d1*d1 + d2*d2 + d3*d3;
  }
  ws[OFF_KGS + br*65536 + r] = s;
}

__global__ void kg_reduce_kernel(float* __restrict__ ws)
{
  int r = blockIdx.x*256 + threadIdx.x;
  float s  = ws[OFF_KGS + r];
  float sn = ws[OFF_KGS + 65536 + r];
  float dif = sn - s;
  float ls = fminf(dif, 0.f) - __logf(1.f + __expf(-fabsf(dif)));
  #pragma unroll
  for (int m2 = 1; m2 < 64; m2 <<= 1) ls += __shfl_xor(ls, m2);
  if ((threadIdx.x & 63) == 0) atomicAdd(ws + OFF_KGSUM, ls);
}

// ---------------- rs_att: one wave per (b, branch) ----------------
__global__ void rsatt_kernel(const float* __restrict__ W_iatt, const float* __restrict__ b_iatt,
                             float* __restrict__ ws)
{
  int gid = blockIdx.x*256 + threadIdx.x;
  int gw = gid >> 6, lane = gid & 63;
  int b = gw >> 1, br = gw & 1;
  const float* selfB = ws + OFF_SELFPN + br*65536 + b*64;
  const float* lcB   = ws + OFF_LCPN   + br*65536 + b*64;
  const float* gbB   = ws + OFF_GBPN   + br*65536 + b*64;
  const float* gvec  = ws + OFF_GVEC;
  const float* selfH = ws + OFF_SELFH;
  const float* hisLC = ws + OFF_HISLC;
  const float* hisGB = ws + OFF_HISGB;

  float gd = gvec[lane];
  float sv = selfB[lane], lcv = lcB[lane], gbv = gbB[lane];
  float gated = gd*lcv + (1.f - gd)*gbv;
  float part = W_iatt[128+lane]*sv + W_iatt[192+lane]*gated;   // item half of logit dot
  #pragma unroll
  for (int m2 = 1; m2 < 64; m2 <<= 1) part += __shfl_xor(part, m2);
  float itemdot = part + b_iatt[0];

  int m = lane & 31, half = lane >> 5;
  long nrow = (long)(b*32 + m)*64;
  float sh = 0.f;
  if (half == 0){
    for (int j4 = 0; j4 < 16; ++j4){
      float4 h4 = ld4(selfH + nrow + 4*j4);
      float4 w4 = ld4(W_iatt + 4*j4);
      sh += w4.x*h4.x + w4.y*h4.y + w4.z*h4.z + w4.w*h4.w;
    }
  } else {
    for (int j4 = 0; j4 < 16; ++j4){
      float4 l4 = ld4(hisLC + nrow + 4*j4);
      float4 g4 = ld4(hisGB + nrow + 4*j4);
      float4 gg = ld4(gvec + 4*j4);
      float4 w4 = ld4(W_iatt + 64 + 4*j4);
      sh += w4.x*(gg.x*l4.x + (1.f-gg.x)*g4.x);
      sh += w4.y*(gg.y*l4.y + (1.f-gg.y)*g4.y);
      sh += w4.z*(gg.z*l4.z + (1.f-gg.z)*g4.z);
      sh += w4.w*(gg.w*l4.w + (1.f-gg.w)*g4.w);
    }
  }
  sh += __shfl_xor(sh, 32);
  float logit = tanh_fast(sh + itemdot);
  float mxv = logit;
  #pragma unroll
  for (int m2 = 1; m2 < 32; m2 <<= 1) mxv = fmaxf(mxv, __shfl_xor(mxv, m2));
  float e = __expf(logit - mxv);
  float se = e;
  #pragma unroll
  for (int m2 = 1; m2 < 32; m2 <<= 1) se += __shfl_xor(se, m2);
  float att = __fdividef(e, se);

  // u_lc[d] (lane=d over 2 halves)
  float u1 = 0.f, u2 = 0.f;
  for (int mm = 0; mm < 32; ++mm){
    float a = __shfl(att, mm);
    long nr = (long)(b*32 + mm)*64;
    float x1 = selfH[nr + lane];
    float x2 = gd*hisLC[nr + lane] + (1.f - gd)*hisGB[nr + lane];
    u1 += a*x1; u2 += a*x2;
  }
  float* upo = ws + OFF_ULCPN + (long)(br*1024 + b)*128;
  upo[lane] = u1; upo[64 + lane] = u2;
}

// ---------------- u-MLP + score: one wave per (b, branch) ----------------
__global__ void umlp_kernel(const float* __restrict__ b_u, float* __restrict__ ws, float* __restrict__ out)
{
  int gid = blockIdx.x*256 + threadIdx.x;
  int gw = gid >> 6, lane = gid & 63;
  int b = gw >> 1, br = gw & 1;
  const float* WuT = ws + OFF_WU;
  const float* ug  = ws + OFF_USERG + b*64;
  const float* ul  = ws + OFF_ULCPN + (long)(br*1024 + b)*128;
  float acc = b_u[lane];
  for (int j = 0; j < 64; ++j)  acc += WuT[j*64 + lane] * ug[j];
  for (int j = 0; j < 128; ++j) acc += WuT[(64 + j)*64 + lane] * ul[j];
  float uo = fmaxf(acc, 0.f);
  float ssv = uo*uo;
  #pragma unroll
  for (int m2 = 1; m2 < 64; m2 <<= 1) ssv += __shfl_xor(ssv, m2);
  float rn = __fdividef(1.f, fmaxf(sqrtf(ssv), 1e-12f));
  float nuo = uo*rn;
  const float* selfB = ws + OFF_SELFPN + br*65536 + b*64;
  const float* lcB   = ws + OFF_LCPN   + br*65536 + b*64;
  const float* gbB   = ws + OFF_GBPN   + br*65536 + b*64;
  float gd = ws[OFF_GVEC + lane];
  float gated = gd*lcB[lane] + (1.f - gd)*gbB[lane];
  float p = ug[lane]*selfB[lane] + nuo*gated;
  #pragma unroll
  for (int m2 = 1; m2 < 64; m2 <<= 1) p += __shfl_xor(p, m2);
  if (lane == 0) out[br*1024 + b] = p;
}

// ---------------- final loss ----------------
__global__ void loss_kernel(const float* __restrict__ ws, float* __restrict__ out)
{
  __shared__ float red[16];
  int t = threadIdx.x;
  float ps = out[t], ns_ = out[1024 + t];
  float dif = ps - ns_;
  float v = fminf(dif, 0.f) - __logf(1.f + __expf(-fabsf(dif)));
  #pragma unroll
  for (int m2 = 1; m2 < 64; m2 <<= 1) v += __shfl_xor(v, m2);
  if ((t & 63) == 0) red[t >> 6] = v;
  __syncthreads();
  if (t == 0){
    float s = 0.f;
    for (int i = 0; i < 16; ++i) s += red[i];
    float rs = -s * (1.f/1024.f);
    float kg = -ws[OFF_KGSUM] * (1.f/65536.f);
    out[2048] = rs + kg;
  }
}

extern "C" void kernel_launch(void* const* d_in, const int* in_sizes, int n_in,
                              void* d_out, int out_size, void* d_ws, size_t ws_size,
                              hipStream_t stream)
{
  const int* user_indices = (const int*)d_in[0];
  const int* ent_his_self = (const int*)d_in[1];
  const int* ent_his_nbr  = (const int*)d_in[2];
  const int* rel_his      = (const int*)d_in[3];
  const int* ent_pos_self = (const int*)d_in[4];
  const int* ent_pos_nbr  = (const int*)d_in[5];
  const int* rel_pos      = (const int*)d_in[6];
  const int* ent_neg_self = (const int*)d_in[7];
  const int* ent_neg_nbr  = (const int*)d_in[8];
  const int* rel_neg      = (const int*)d_in[9];
  const int* gb_his_self  = (const int*)d_in[10];
  const int* gb_his_path  = (const int*)d_in[11];
  const int* gb_pos_self  = (const int*)d_in[12];
  const int* gb_pos_path  = (const int*)d_in[13];
  const int* gb_neg_self  = (const int*)d_in[14];
  const int* gb_neg_path  = (const int*)d_in[15];
  const int* kg_head      = (const int*)d_in[16];
  const int* kg_rel       = (const int*)d_in[17];
  const int* kg_tail      = (const int*)d_in[18];
  const int* kg_tail_neg  = (const int*)d_in[19];
  const float* entity_emb   = (const float*)d_in[20];
  const float* relation_emb = (const float*)d_in[21];
  const float* user_emb     = (const float*)d_in[22];
  const float* gate         = (const float*)d_in[23];
  const float* W_u_mlp      = (const float*)d_in[24];
  const float* b_u_mlp      = (const float*)d_in[25];
  const float* W_re         = (const float*)d_in[26];
  const float* W_agg        = (const float*)d_in[27];
  const float* b_agg        = (const float*)d_in[28];
  const float* W_gatt       = (const float*)d_in[29];
  const float* b_gatt       = (const float*)d_in[30];
  const float* W_iatt       = (const float*)d_in[31];
  const float* b_iatt       = (const float*)d_in[32];
  const float* W_tatt       = (const float*)d_in[33];
  const float* b_tatt       = (const float*)d_in[34];
  const float* W_ih         = (const float*)d_in[35];
  const float* W_hh         = (const float*)d_in[36];
  const float* b_ih         = (const float*)d_in[37];
  const float* b_hh         = (const float*)d_in[38];
  float* ws  = (float*)d_ws;
  float* out = (float*)d_out;

  (void)hipMemsetAsync(ws + OFF_KGSUM, 0, sizeof(float), stream);
  prep_kernel<<<1, 256, 0, stream>>>(W_tatt, W_gatt, W_re, W_agg, W_u_mlp, gate, ws);
  user_prep_kernel<<<256, 256, 0, stream>>>(user_indices, user_emb, b_tatt, ws);
  agg2_kernel<<<ROWS/16, 256, 0, stream>>>(
      ent_his_self, ent_his_nbr, rel_his,
      ent_pos_self, ent_pos_nbr, rel_pos,
      ent_neg_self, ent_neg_nbr, rel_neg,
      entity_emb, relation_emb, b_gatt, b_agg, ws);
  gru2_kernel<<<ROWS/64, 256, 0, stream>>>(
      gb_his_self, gb_his_path, gb_pos_self, gb_pos_path,
      gb_neg_self, gb_neg_path, entity_emb,
      W_ih, W_hh, b_ih, b_hh, W_agg, b_agg, ws);
  kg2_kernel<<<512, 256, 0, stream>>>(kg_head, kg_rel, kg_tail, kg_tail_neg,
                                      entity_emb, relation_emb, ws);
  kg_reduce_kernel<<<256, 256, 0, stream>>>(ws);
  rsatt_kernel<<<512, 256, 0, stream>>>(W_iatt, b_iatt, ws);
  umlp_kernel<<<512, 256, 0, stream>>>(b_u_mlp, ws, out);
  loss_kernel<<<1, 1024, 0, stream>>>(ws, out);
}

// Round 6
// 2689.334 us; speedup vs baseline: 2.3246x; 2.3246x over previous
//
#include <hip/hip_runtime.h>

#define DEV __device__ __forceinline__

#define Dd   64
#define Bb   1024
#define Mm   32
#define Kk   16
#define Ll   8
#define NKGk 65536
#define NH   32768            // B*M
#define ROWS (NH + 2*Bb)      // 34816

// ---- workspace layout (float offsets) ----
#define OFF_WTATT   0          // 64x64  transposed W_tatt
#define OFF_WGS     4096       // 64x64  transposed W_gatt[:, :64]   (WgsT[j*64+d] = W_gatt[d][j])
#define OFF_WCOMB   8192       // 128x64 transposed (W_gatt[:,64:] @ W_re)
#define OFF_WRE     16384      // 128x64 transposed W_re
#define OFF_WAGG    24576      // 128x64 transposed W_agg (WaggT[j*64+d] = W_agg[d][j], j<128)
#define OFF_WU      32768      // 192x64 transposed W_u_mlp
#define OFF_GVEC    45056      // 64     sigmoid(gate)
#define OFF_USERG   45120      // 1024x64
#define OFF_UATT    110656     // 1024x64
#define OFF_SELFH   176192     // 32768x64
#define OFF_HISLC   2273344    // 32768x64
#define OFF_HISGB   4370496    // 32768x64
#define OFF_SELFPN  6467648    // 2x1024x64 (pos, then neg)
#define OFF_LCPN    6598720    // 2x1024x64
#define OFF_GBPN    6729792    // 2x1024x64
#define OFF_ULCPN   6860864    // 2x1024x128
#define OFF_KGSUM   7123008    // 1
#define OFF_KGS     7123012    // 2x65536 kg squared distances (pos, neg)

DEV float4 ld4(const float* p){ return *reinterpret_cast<const float4*>(p); }
DEV void st4(float* p, const float4 v){ *reinterpret_cast<float4*>(p) = v; }

DEV float tanh_fast(float x){
  float cx = fminf(15.f, fmaxf(-15.f, x));
  float e = __expf(2.f*cx);
  return __fdividef(e - 1.f, e + 1.f);
}
DEV float sigmoid_fast(float x){ return __fdividef(1.f, 1.f + __expf(-x)); }

// acc[d] += W^T rows (4 consecutive) dotted against a float4 of x.
// W_ points at 256 contiguous floats (4 rows x 64) -> wave-uniform s_loads.
// NOTE: macro params must not collide with .x/.y/.z/.w member tokens.
#define MV4(ACC_, W_, X4_) \
  { _Pragma("unroll") for (int d_ = 0; d_ < 64; ++d_) ACC_[d_] += (W_)[d_]       * (X4_).x; \
    _Pragma("unroll") for (int d_ = 0; d_ < 64; ++d_) ACC_[d_] += (W_)[64 + d_]  * (X4_).y; \
    _Pragma("unroll") for (int d_ = 0; d_ < 64; ++d_) ACC_[d_] += (W_)[128 + d_] * (X4_).z; \
    _Pragma("unroll") for (int d_ = 0; d_ < 64; ++d_) ACC_[d_] += (W_)[192 + d_] * (X4_).w; }

// ---------------- prep: weight transposes, Wcomb fold, gate sigmoid ----------------
__global__ void prep_kernel(const float* __restrict__ W_tatt, const float* __restrict__ W_gatt,
                            const float* __restrict__ W_re, const float* __restrict__ W_agg,
                            const float* __restrict__ W_u, const float* __restrict__ gate,
                            float* __restrict__ ws)
{
  int t = threadIdx.x;
  for (int i = t; i < 4096; i += 256){
    int d = i >> 6, j = i & 63;
    ws[OFF_WTATT + j*64 + d] = W_tatt[i];            // W_tatt (64,64)
    ws[OFF_WGS   + j*64 + d] = W_gatt[d*128 + j];    // self half of W_gatt
  }
  for (int i = t; i < 8192; i += 256){
    int j = i >> 6, d = i & 63;
    ws[OFF_WRE  + i] = W_re[d*128 + j];
    ws[OFF_WAGG + i] = W_agg[d*128 + j];
    float s = 0.f;
    for (int dp = 0; dp < 64; ++dp) s += W_gatt[d*128 + 64 + dp] * W_re[dp*128 + j];
    ws[OFF_WCOMB + i] = s;                           // (W_gatt[:,64:] @ W_re)^T
  }
  for (int i = t; i < 12288; i += 256){
    int j = i >> 6, d = i & 63;
    ws[OFF_WU + i] = W_u[d*192 + j];
  }
  if (t < 64) ws[OFF_GVEC + t] = sigmoid_fast(gate[t]);
}

// ---------------- user gather + u_att = relu(user_g @ W_tatt^T + b_tatt) ----------------
__global__ void user_prep_kernel(const int* __restrict__ uidx, const float* __restrict__ user_emb,
                                 const float* __restrict__ b_tatt, float* __restrict__ ws)
{
  int gid = blockIdx.x*256 + threadIdx.x;
  int b = gid >> 6, lane = gid & 63;
  long ui = uidx[b];
  float ugd = user_emb[ui*64 + lane];
  ws[OFF_USERG + b*64 + lane] = ugd;
  const float* WtT = ws + OFF_WTATT;
  float acc = b_tatt[lane];
  for (int j = 0; j < 64; ++j) acc += WtT[j*64 + lane] * __shfl(ugd, j);
  ws[OFF_UATT + b*64 + lane] = fmaxf(acc, 0.f);
}

// ---------------- agg_lc v2: thread = (row, k); 16 rows x 16 k per block ----------------
__global__ __launch_bounds__(256) void agg2_kernel(
  const int* __restrict__ hS, const int* __restrict__ hN, const int* __restrict__ hR,
  const int* __restrict__ pS, const int* __restrict__ pN, const int* __restrict__ pR,
  const int* __restrict__ nS, const int* __restrict__ nN, const int* __restrict__ nR,
  const float* __restrict__ entity, const float* __restrict__ relation,
  const float* __restrict__ b_gatt, const float* __restrict__ b_agg,
  float* __restrict__ ws)
{
  int tid = threadIdx.x;
  int k = tid & 15, rl = tid >> 4;          // k-lane, row-in-block
  int rbase = blockIdx.x*16;
  const int *sI, *nI, *rI; float *sO, *aO; int nb0, uhis;
  if (rbase < NH)          { sI=hS; nI=hN; rI=hR; sO=ws+OFF_SELFH;        aO=ws+OFF_HISLC;       nb0=rbase;        uhis=1; }
  else if (rbase < NH+Bb)  { sI=pS; nI=pN; rI=pR; sO=ws+OFF_SELFPN;       aO=ws+OFF_LCPN;       nb0=rbase-NH;     uhis=0; }
  else                     { sI=nS; nI=nN; rI=nR; sO=ws+OFF_SELFPN+65536; aO=ws+OFF_LCPN+65536; nb0=rbase-NH-Bb;  uhis=0; }
  int n = nb0 + rl;
  int urow = uhis ? (n >> 5) : n;

  const float* es = entity + (long)sI[n]*64;
  // ---- sc part: lane owns outputs o = k*4 .. k*4+3 of  sc = b_gatt + Wg_self@self ----
  const float* WgsT = ws + OFF_WGS;
  float4 sc4 = ld4(b_gatt + k*4);
  for (int j4 = 0; j4 < 16; ++j4){
    float4 s4 = ld4(es + 4*j4);
    float4 w0 = ld4(WgsT + (4*j4+0)*64 + k*4);
    float4 w1 = ld4(WgsT + (4*j4+1)*64 + k*4);
    float4 w2 = ld4(WgsT + (4*j4+2)*64 + k*4);
    float4 w3 = ld4(WgsT + (4*j4+3)*64 + k*4);
    sc4.x += w0.x*s4.x + w1.x*s4.y + w2.x*s4.z + w3.x*s4.w;
    sc4.y += w0.y*s4.x + w1.y*s4.y + w2.y*s4.z + w3.y*s4.w;
    sc4.z += w0.z*s4.x + w1.z*s4.y + w2.z*s4.z + w3.z*s4.w;
    sc4.w += w0.w*s4.x + w1.w*s4.y + w2.w*s4.z + w3.w*s4.w;
  }
  // store self_v chunk (lane k stores dims k*4..k*4+3)
  st4(sO + (long)n*64 + k*4, ld4(es + k*4));

  // ---- neighbor matvec: acc = Wcomb @ [nbr | rel]  (wave-uniform s_load weights) ----
  long nbI = nI[n*16 + k], rlI = rI[n*16 + k];
  const float* en = entity + nbI*64;
  const float* er = relation + rlI*64;
  float xnb[64];
  #pragma unroll
  for (int j4 = 0; j4 < 16; ++j4){
    float4 x4 = ld4(en + 4*j4);
    xnb[4*j4+0] = x4.x; xnb[4*j4+1] = x4.y; xnb[4*j4+2] = x4.z; xnb[4*j4+3] = x4.w;
  }
  float acc[64];
  #pragma unroll
  for (int d = 0; d < 64; ++d) acc[d] = 0.f;
  const float* WcT = ws + OFF_WCOMB;
  for (int j4 = 0; j4 < 16; ++j4){
    float4 x4 = ld4(en + 4*j4);
    MV4(acc, WcT + j4*256, x4);
  }
  for (int j4 = 0; j4 < 16; ++j4){
    float4 x4 = ld4(er + 4*j4);
    MV4(acc, WcT + 4096 + j4*256, x4);
  }
  // ---- logit = u_att . tanh(sc + acc)  (sc broadcast from owner lanes) ----
  int gl = (tid & 63) & 48;                 // group base lane within wave
  const float* up = ws + OFF_UATT + (long)urow*64;
  float lg = 0.f;
  #pragma unroll
  for (int j4 = 0; j4 < 16; ++j4){
    float4 u4 = ld4(up + 4*j4);
    float s0 = __shfl(sc4.x, gl + j4);
    float s1 = __shfl(sc4.y, gl + j4);
    float s2 = __shfl(sc4.z, gl + j4);
    float s3 = __shfl(sc4.w, gl + j4);
    lg += u4.x*tanh_fast(acc[4*j4+0] + s0);
    lg += u4.y*tanh_fast(acc[4*j4+1] + s1);
    lg += u4.z*tanh_fast(acc[4*j4+2] + s2);
    lg += u4.w*tanh_fast(acc[4*j4+3] + s3);
  }
  // ---- softmax over the 16 k-lanes ----
  float mx = lg;
  mx = fmaxf(mx, __shfl_xor(mx, 1)); mx = fmaxf(mx, __shfl_xor(mx, 2));
  mx = fmaxf(mx, __shfl_xor(mx, 4)); mx = fmaxf(mx, __shfl_xor(mx, 8));
  float e = __expf(lg - mx);
  float se = e;
  se += __shfl_xor(se, 1); se += __shfl_xor(se, 2);
  se += __shfl_xor(se, 4); se += __shfl_xor(se, 8);
  float att = __fdividef(e, se);
  // ---- agg: lane computes outputs o = k*4..k*4+3 of tanh(W_agg@[self|new_v]+b) ----
  const float* WaT = ws + OFF_WAGG;
  float4 a4 = ld4(b_agg + k*4);
  for (int j4 = 0; j4 < 16; ++j4){          // self half (streamed, L1-hot)
    float4 s4 = ld4(es + 4*j4);
    float4 w0 = ld4(WaT + (4*j4+0)*64 + k*4);
    float4 w1 = ld4(WaT + (4*j4+1)*64 + k*4);
    float4 w2 = ld4(WaT + (4*j4+2)*64 + k*4);
    float4 w3 = ld4(WaT + (4*j4+3)*64 + k*4);
    a4.x += w0.x*s4.x + w1.x*s4.y + w2.x*s4.z + w3.x*s4.w;
    a4.y += w0.y*s4.x + w1.y*s4.y + w2.y*s4.z + w3.y*s4.w;
    a4.z += w0.z*s4.x + w1.z*s4.y + w2.z*s4.z + w3.z*s4.w;
    a4.w += w0.w*s4.x + w1.w*s4.y + w2.w*s4.z + w3.w*s4.w;
  }
  #pragma unroll
  for (int j = 0; j < 64; ++j){             // new_v half via 16-lane butterfly
    float v = att * xnb[j];
    v += __shfl_xor(v, 1); v += __shfl_xor(v, 2);
    v += __shfl_xor(v, 4); v += __shfl_xor(v, 8);
    float4 wv = ld4(WaT + (64+j)*64 + k*4);
    a4.x += wv.x*v; a4.y += wv.y*v; a4.z += wv.z*v; a4.w += wv.w*v;
  }
  float t0 = tanh_fast(a4.x), t1 = tanh_fast(a4.y), t2 = tanh_fast(a4.z), t3 = tanh_fast(a4.w);
  float ss = t0*t0 + t1*t1 + t2*t2 + t3*t3;
  ss += __shfl_xor(ss, 1); ss += __shfl_xor(ss, 2);
  ss += __shfl_xor(ss, 4); ss += __shfl_xor(ss, 8);
  float rn = __fdividef(1.f, fmaxf(sqrtf(ss), 1e-12f));
  float4 o4; o4.x = t0*rn; o4.y = t1*rn; o4.z = t2*rn; o4.w = t3*rn;
  st4(aO + (long)n*64 + k*4, o4);
}

// ---------------- GRU v4: block = 64 rows x 4 waves; wave w owns outputs [w*16,w*16+16) ----
// v3 fix kept: h_prev[o] from LDS (no dynamic VGPR index).
// v4 fix: NO min-waves launch bound -- (256,3) capped VGPRs and spilled x[64]/hc[64]
//         entirely to scratch (9.4 GB HBM traffic, 5.3 ms). Let allocator use ~200 VGPRs.
__global__ __launch_bounds__(256) void gru2_kernel(
  const int* __restrict__ hS, const int* __restrict__ hP,
  const int* __restrict__ pS, const int* __restrict__ pP,
  const int* __restrict__ nS, const int* __restrict__ nP,
  const float* __restrict__ entity,
  const float* __restrict__ W_ih, const float* __restrict__ W_hh,
  const float* __restrict__ b_ih, const float* __restrict__ b_hh,
  const float* __restrict__ W_agg, const float* __restrict__ b_agg,
  float* __restrict__ ws)
{
  __shared__ float hb[2][64][64];           // [buf][dim][row] double-buffered h
  int tid = threadIdx.x;
  int w = __builtin_amdgcn_readfirstlane(tid >> 6);
  int lane = tid & 63;
  int rbase = blockIdx.x*64;
  const int *sIv, *pIv; float* aO; int nb0;
  if (rbase < NH)          { sIv=hS; pIv=hP; aO=ws+OFF_HISGB;        nb0=rbase; }
  else if (rbase < NH+Bb)  { sIv=pS; pIv=pP; aO=ws+OFF_GBPN;        nb0=rbase-NH; }
  else                     { sIv=nS; pIv=nP; aO=ws+OFF_GBPN+65536;  nb0=rbase-NH-Bb; }
  int n = nb0 + lane;

  for (int i = tid; i < 4096; i += 256) ((float*)hb)[i] = 0.f;   // zero buffer 0
  int o0 = w*16;
  int pt = pIv[n*8];
  __syncthreads();

  for (int t = 0; t < 8; ++t){
    int ptn = (t < 7) ? pIv[n*8 + t + 1] : 0;
    const float* ex = entity + (long)pt*64;
    float x[64];
    #pragma unroll
    for (int j4 = 0; j4 < 16; ++j4){
      float4 v = ld4(ex + 4*j4);
      x[4*j4] = v.x; x[4*j4+1] = v.y; x[4*j4+2] = v.z; x[4*j4+3] = v.w;
    }
    int cur = t & 1, nxt = cur ^ 1;
    float hc[64];
    #pragma unroll
    for (int j = 0; j < 64; ++j) hc[j] = hb[cur][j][lane];
    for (int i = 0; i < 16; ++i){
      int o = o0 + i;
      float air = b_ih[o], aiz = b_ih[64+o], ain = b_ih[128+o];
      float ahr = b_hh[o], ahz = b_hh[64+o], ahn = b_hh[128+o];
      const float* wi0 = W_ih + o*64;  const float* wi1 = W_ih + (64+o)*64;  const float* wi2 = W_ih + (128+o)*64;
      const float* wh0 = W_hh + o*64;  const float* wh1 = W_hh + (64+o)*64;  const float* wh2 = W_hh + (128+o)*64;
      #pragma unroll
      for (int j = 0; j < 64; ++j){
        air += wi0[j]*x[j]; aiz += wi1[j]*x[j]; ain += wi2[j]*x[j];
        ahr += wh0[j]*hc[j]; ahz += wh1[j]*hc[j]; ahn += wh2[j]*hc[j];
      }
      float r  = sigmoid_fast(air + ahr);
      float z  = sigmoid_fast(aiz + ahz);
      float nn = tanh_fast(ain + r*ahn);
      float hprev = hb[cur][o][lane];          // LDS read, NOT dynamic reg index
      hb[nxt][o][lane] = (1.f - z)*nn + z*hprev;
    }
    pt = ptn;
    __syncthreads();
  }
  // final h in hb[0]. agg = normalize(tanh(W_agg@[self|hT]+b_agg))
  const float* es = entity + (long)sIv[n]*64;
  float sv[64];
  #pragma unroll
  for (int j4 = 0; j4 < 16; ++j4){
    float4 v = ld4(es + 4*j4);
    sv[4*j4] = v.x; sv[4*j4+1] = v.y; sv[4*j4+2] = v.z; sv[4*j4+3] = v.w;
  }
  float hT[64];
  #pragma unroll
  for (int j = 0; j < 64; ++j) hT[j] = hb[0][j][lane];
  __syncthreads();                                    // before reusing hb[1] as transpose buf
  for (int i = 0; i < 16; ++i){
    int o = o0 + i;
    float a = b_agg[o];
    const float* wr = W_agg + (long)o*128;
    #pragma unroll
    for (int j = 0; j < 64; ++j) a += wr[j]*sv[j];
    #pragma unroll
    for (int j = 0; j < 64; ++j) a += wr[64+j]*hT[j];
    hb[1][o][lane] = tanh_fast(a);
  }
  __syncthreads();
  // normalize + coalesced store: thread (q = tid&3, r = tid>>2)
  int q = tid & 3, r = tid >> 2;
  float vv[16];
  float ss = 0.f;
  #pragma unroll
  for (int jj = 0; jj < 16; ++jj){ float v = hb[1][q*16+jj][r]; vv[jj] = v; ss += v*v; }
  ss += __shfl_xor(ss, 1); ss += __shfl_xor(ss, 2);
  float rn = __fdividef(1.f, fmaxf(sqrtf(ss), 1e-12f));
  int n2 = nb0 + r;
  #pragma unroll
  for (int jj4 = 0; jj4 < 4; ++jj4){
    float4 o4; o4.x = vv[4*jj4]*rn; o4.y = vv[4*jj4+1]*rn; o4.z = vv[4*jj4+2]*rn; o4.w = vv[4*jj4+3]*rn;
    st4(aO + (long)n2*64 + q*16 + 4*jj4, o4);
  }
}

// ---------------- KG v2: thread = (r, branch); store squared distances ----------------
__global__ __launch_bounds__(256) void kg2_kernel(
  const int* __restrict__ kh, const int* __restrict__ kr,
  const int* __restrict__ kt, const int* __restrict__ ktn,
  const float* __restrict__ entity, const float* __restrict__ relation,
  float* __restrict__ ws)
{
  int tid = threadIdx.x;
  int br = blockIdx.x >> 8;
  int r  = (blockIdx.x & 255)*256 + tid;
  const int* tailI = br ? ktn : kt;
  const float* WreT = ws + OFF_WRE;
  const float* er = relation + (long)kr[r]*64;
  const float* et = entity + (long)tailI[r]*64;
  float acc[64];
  #pragma unroll
  for (int d = 0; d < 64; ++d) acc[d] = 0.f;
  for (int j4 = 0; j4 < 16; ++j4){
    float4 x4 = ld4(et + 4*j4);
    MV4(acc, WreT + j4*256, x4);
  }
  for (int j4 = 0; j4 < 16; ++j4){
    float4 x4 = ld4(er + 4*j4);
    MV4(acc, WreT + 4096 + j4*256, x4);
  }
  const float* eh = entity + (long)kh[r]*64;
  float s = 0.f;
  #pragma unroll
  for (int j4 = 0; j4 < 16; ++j4){
    float4 h4 = ld4(eh + 4*j4);
    float d0 = h4.x - acc[4*j4+0], d1 = h4.y - acc[4*j4+1];
    float d2 = h4.z - acc[4*j4+2], d3 = h4.w - acc[4*j4+3];
    s += d0*d0 + d1*d1 + d2*d2 + d3*d3;
  }
  ws[OFF_KGS + br*65536 + r] = s;
}

__global__ void kg_reduce_kernel(float* __restrict__ ws)
{
  int r = blockIdx.x*256 + threadIdx.x;
  float s  = ws[OFF_KGS + r];
  float sn = ws[OFF_KGS + 65536 + r];
  float dif = sn - s;
  float ls = fminf(dif, 0.f) - __logf(1.f + __expf(-fabsf(dif)));
  #pragma unroll
  for (int m2 = 1; m2 < 64; m2 <<= 1) ls += __shfl_xor(ls, m2);
  if ((threadIdx.x & 63) == 0) atomicAdd(ws + OFF_KGSUM, ls);
}

// ---------------- rs_att: one wave per (b, branch) ----------------
__global__ void rsatt_kernel(const float* __restrict__ W_iatt, const float* __restrict__ b_iatt,
                             float* __restrict__ ws)
{
  int gid = blockIdx.x*256 + threadIdx.x;
  int gw = gid >> 6, lane = gid & 63;
  int b = gw >> 1, br = gw & 1;
  const float* selfB = ws + OFF_SELFPN + br*65536 + b*64;
  const float* lcB   = ws + OFF_LCPN   + br*65536 + b*64;
  const float* gbB   = ws + OFF_GBPN   + br*65536 + b*64;
  const float* gvec  = ws + OFF_GVEC;
  const float* selfH = ws + OFF_SELFH;
  const float* hisLC = ws + OFF_HISLC;
  const float* hisGB = ws + OFF_HISGB;

  float gd = gvec[lane];
  float sv = selfB[lane], lcv = lcB[lane], gbv = gbB[lane];
  float gated = gd*lcv + (1.f - gd)*gbv;
  float part = W_iatt[128+lane]*sv + W_iatt[192+lane]*gated;   // item half of logit dot
  #pragma unroll
  for (int m2 = 1; m2 < 64; m2 <<= 1) part += __shfl_xor(part, m2);
  float itemdot = part + b_iatt[0];

  int m = lane & 31, half = lane >> 5;
  long nrow = (long)(b*32 + m)*64;
  float sh = 0.f;
  if (half == 0){
    for (int j4 = 0; j4 < 16; ++j4){
      float4 h4 = ld4(selfH + nrow + 4*j4);
      float4 w4 = ld4(W_iatt + 4*j4);
      sh += w4.x*h4.x + w4.y*h4.y + w4.z*h4.z + w4.w*h4.w;
    }
  } else {
    for (int j4 = 0; j4 < 16; ++j4){
      float4 l4 = ld4(hisLC + nrow + 4*j4);
      float4 g4 = ld4(hisGB + nrow + 4*j4);
      float4 gg = ld4(gvec + 4*j4);
      float4 w4 = ld4(W_iatt + 64 + 4*j4);
      sh += w4.x*(gg.x*l4.x + (1.f-gg.x)*g4.x);
      sh += w4.y*(gg.y*l4.y + (1.f-gg.y)*g4.y);
      sh += w4.z*(gg.z*l4.z + (1.f-gg.z)*g4.z);
      sh += w4.w*(gg.w*l4.w + (1.f-gg.w)*g4.w);
    }
  }
  sh += __shfl_xor(sh, 32);
  float logit = tanh_fast(sh + itemdot);
  float mxv = logit;
  #pragma unroll
  for (int m2 = 1; m2 < 32; m2 <<= 1) mxv = fmaxf(mxv, __shfl_xor(mxv, m2));
  float e = __expf(logit - mxv);
  float se = e;
  #pragma unroll
  for (int m2 = 1; m2 < 32; m2 <<= 1) se += __shfl_xor(se, m2);
  float att = __fdividef(e, se);

  // u_lc[d] (lane=d over 2 halves)
  float u1 = 0.f, u2 = 0.f;
  for (int mm = 0; mm < 32; ++mm){
    float a = __shfl(att, mm);
    long nr = (long)(b*32 + mm)*64;
    float x1 = selfH[nr + lane];
    float x2 = gd*hisLC[nr + lane] + (1.f - gd)*hisGB[nr + lane];
    u1 += a*x1; u2 += a*x2;
  }
  float* upo = ws + OFF_ULCPN + (long)(br*1024 + b)*128;
  upo[lane] = u1; upo[64 + lane] = u2;
}

// ---------------- u-MLP + score: one wave per (b, branch) ----------------
__global__ void umlp_kernel(const float* __restrict__ b_u, float* __restrict__ ws, float* __restrict__ out)
{
  int gid = blockIdx.x*256 + threadIdx.x;
  int gw = gid >> 6, lane = gid & 63;
  int b = gw >> 1, br = gw & 1;
  const float* WuT = ws + OFF_WU;
  const float* ug  = ws + OFF_USERG + b*64;
  const float* ul  = ws + OFF_ULCPN + (long)(br*1024 + b)*128;
  float acc = b_u[lane];
  for (int j = 0; j < 64; ++j)  acc += WuT[j*64 + lane] * ug[j];
  for (int j = 0; j < 128; ++j) acc += WuT[(64 + j)*64 + lane] * ul[j];
  float uo = fmaxf(acc, 0.f);
  float ssv = uo*uo;
  #pragma unroll
  for (int m2 = 1; m2 < 64; m2 <<= 1) ssv += __shfl_xor(ssv, m2);
  float rn = __fdividef(1.f, fmaxf(sqrtf(ssv), 1e-12f));
  float nuo = uo*rn;
  const float* selfB = ws + OFF_SELFPN + br*65536 + b*64;
  const float* lcB   = ws + OFF_LCPN   + br*65536 + b*64;
  const float* gbB   = ws + OFF_GBPN   + br*65536 + b*64;
  float gd = ws[OFF_GVEC + lane];
  float gated = gd*lcB[lane] + (1.f - gd)*gbB[lane];
  float p = ug[lane]*selfB[lane] + nuo*gated;
  #pragma unroll
  for (int m2 = 1; m2 < 64; m2 <<= 1) p += __shfl_xor(p, m2);
  if (lane == 0) out[br*1024 + b] = p;
}

// ---------------- final loss ----------------
__global__ void loss_kernel(const float* __restrict__ ws, float* __restrict__ out)
{
  __shared__ float red[16];
  int t = threadIdx.x;
  float ps = out[t], ns_ = out[1024 + t];
  float dif = ps - ns_;
  float v = fminf(dif, 0.f) - __logf(1.f + __expf(-fabsf(dif)));
  #pragma unroll
  for (int m2 = 1; m2 < 64; m2 <<= 1) v += __shfl_xor(v, m2);
  if ((t & 63) == 0) red[t >> 6] = v;
  __syncthreads();
  if (t == 0){
    float s = 0.f;
    for (int i = 0; i < 16; ++i) s += red[i];
    float rs = -s * (1.f/1024.f);
    float kg = -ws[OFF_KGSUM] * (1.f/65536.f);
    out[2048] = rs + kg;
  }
}

extern "C" void kernel_launch(void* const* d_in, const int* in_sizes, int n_in,
                              void* d_out, int out_size, void* d_ws, size_t ws_size,
                              hipStream_t stream)
{
  const int* user_indices = (const int*)d_in[0];
  const int* ent_his_self = (const int*)d_in[1];
  const int* ent_his_nbr  = (const int*)d_in[2];
  const int* rel_his      = (const int*)d_in[3];
  const int* ent_pos_self = (const int*)d_in[4];
  const int* ent_pos_nbr  = (const int*)d_in[5];
  const int* rel_pos      = (const int*)d_in[6];
  const int* ent_neg_self = (const int*)d_in[7];
  const int* ent_neg_nbr  = (const int*)d_in[8];
  const int* rel_neg      = (const int*)d_in[9];
  const int* gb_his_self  = (const int*)d_in[10];
  const int* gb_his_path  = (const int*)d_in[11];
  const int* gb_pos_self  = (const int*)d_in[12];
  const int* gb_pos_path  = (const int*)d_in[13];
  const int* gb_neg_self  = (const int*)d_in[14];
  const int* gb_neg_path  = (const int*)d_in[15];
  const int* kg_head      = (const int*)d_in[16];
  const int* kg_rel       = (const int*)d_in[17];
  const int* kg_tail      = (const int*)d_in[18];
  const int* kg_tail_neg  = (const int*)d_in[19];
  const float* entity_emb   = (const float*)d_in[20];
  const float* relation_emb = (const float*)d_in[21];
  const float* user_emb     = (const float*)d_in[22];
  const float* gate         = (const float*)d_in[23];
  const float* W_u_mlp      = (const float*)d_in[24];
  const float* b_u_mlp      = (const float*)d_in[25];
  const float* W_re         = (const float*)d_in[26];
  const float* W_agg        = (const float*)d_in[27];
  const float* b_agg        = (const float*)d_in[28];
  const float* W_gatt       = (const float*)d_in[29];
  const float* b_gatt       = (const float*)d_in[30];
  const float* W_iatt       = (const float*)d_in[31];
  const float* b_iatt       = (const float*)d_in[32];
  const float* W_tatt       = (const float*)d_in[33];
  const float* b_tatt       = (const float*)d_in[34];
  const float* W_ih         = (const float*)d_in[35];
  const float* W_hh         = (const float*)d_in[36];
  const float* b_ih         = (const float*)d_in[37];
  const float* b_hh         = (const float*)d_in[38];
  float* ws  = (float*)d_ws;
  float* out = (float*)d_out;

  (void)hipMemsetAsync(ws + OFF_KGSUM, 0, sizeof(float), stream);
  prep_kernel<<<1, 256, 0, stream>>>(W_tatt, W_gatt, W_re, W_agg, W_u_mlp, gate, ws);
  user_prep_kernel<<<256, 256, 0, stream>>>(user_indices, user_emb, b_tatt, ws);
  agg2_kernel<<<ROWS/16, 256, 0, stream>>>(
      ent_his_self, ent_his_nbr, rel_his,
      ent_pos_self, ent_pos_nbr, rel_pos,
      ent_neg_self, ent_neg_nbr, rel_neg,
      entity_emb, relation_emb, b_gatt, b_agg, ws);
  gru2_kernel<<<ROWS/64, 256, 0, stream>>>(
      gb_his_self, gb_his_path, gb_pos_self, gb_pos_path,
      gb_neg_self, gb_neg_path, entity_emb,
      W_ih, W_hh, b_ih, b_hh, W_agg, b_agg, ws);
  kg2_kernel<<<512, 256, 0, stream>>>(kg_head, kg_rel, kg_tail, kg_tail_neg,
                                      entity_emb, relation_emb, ws);
  kg_reduce_kernel<<<256, 256, 0, stream>>>(ws);
  rsatt_kernel<<<512, 256, 0, stream>>>(W_iatt, b_iatt, ws);
  umlp_kernel<<<512, 256, 0, stream>>>(b_u_mlp, ws, out);
  loss_kernel<<<1, 1024, 0, stream>>>(ws, out);
}

// Round 7
// 1715.971 us; speedup vs baseline: 3.6433x; 1.5672x over previous
//
#include <hip/hip_runtime.h>

#define DEV __device__ __forceinline__

#define Dd   64
#define Bb   1024
#define Mm   32
#define Kk   16
#define Ll   8
#define NKGk 65536
#define NH   32768            // B*M
#define ROWS (NH + 2*Bb)      // 34816

// ---- workspace layout (float offsets) ----
#define OFF_WTATT   0          // 64x64  transposed W_tatt
#define OFF_WGS     4096       // 64x64  transposed W_gatt[:, :64]   (WgsT[j*64+d] = W_gatt[d][j])
#define OFF_WCOMB   8192       // 128x64 transposed (W_gatt[:,64:] @ W_re)
#define OFF_WRE     16384      // 128x64 transposed W_re
#define OFF_WAGG    24576      // 128x64 transposed W_agg (WaggT[j*64+d] = W_agg[d][j], j<128)
#define OFF_WU      32768      // 192x64 transposed W_u_mlp
#define OFF_GVEC    45056      // 64     sigmoid(gate)
#define OFF_USERG   45120      // 1024x64
#define OFF_UATT    110656     // 1024x64
#define OFF_SELFH   176192     // 32768x64
#define OFF_HISLC   2273344    // 32768x64
#define OFF_HISGB   4370496    // 32768x64
#define OFF_SELFPN  6467648    // 2x1024x64 (pos, then neg)
#define OFF_LCPN    6598720    // 2x1024x64
#define OFF_GBPN    6729792    // 2x1024x64
#define OFF_ULCPN   6860864    // 2x1024x128
#define OFF_KGSUM   7123008    // 1
#define OFF_KGS     7123012    // 2x65536 kg squared distances (pos, neg)

DEV float4 ld4(const float* p){ return *reinterpret_cast<const float4*>(p); }
DEV void st4(float* p, const float4 v){ *reinterpret_cast<float4*>(p) = v; }

DEV float tanh_fast(float x){
  float cx = fminf(15.f, fmaxf(-15.f, x));
  float e = __expf(2.f*cx);
  return __fdividef(e - 1.f, e + 1.f);
}
DEV float sigmoid_fast(float x){ return __fdividef(1.f, 1.f + __expf(-x)); }

// acc[d] += W^T rows (4 consecutive) dotted against a float4 of x.
// W_ points at 256 contiguous floats (4 rows x 64) -> wave-uniform s_loads.
// NOTE: macro params must not collide with .x/.y/.z/.w member tokens.
#define MV4(ACC_, W_, X4_) \
  { _Pragma("unroll") for (int d_ = 0; d_ < 64; ++d_) ACC_[d_] += (W_)[d_]       * (X4_).x; \
    _Pragma("unroll") for (int d_ = 0; d_ < 64; ++d_) ACC_[d_] += (W_)[64 + d_]  * (X4_).y; \
    _Pragma("unroll") for (int d_ = 0; d_ < 64; ++d_) ACC_[d_] += (W_)[128 + d_] * (X4_).z; \
    _Pragma("unroll") for (int d_ = 0; d_ < 64; ++d_) ACC_[d_] += (W_)[192 + d_] * (X4_).w; }

// ---------------- prep: weight transposes, Wcomb fold, gate sigmoid ----------------
__global__ void prep_kernel(const float* __restrict__ W_tatt, const float* __restrict__ W_gatt,
                            const float* __restrict__ W_re, const float* __restrict__ W_agg,
                            const float* __restrict__ W_u, const float* __restrict__ gate,
                            float* __restrict__ ws)
{
  int t = threadIdx.x;
  for (int i = t; i < 4096; i += 256){
    int d = i >> 6, j = i & 63;
    ws[OFF_WTATT + j*64 + d] = W_tatt[i];            // W_tatt (64,64)
    ws[OFF_WGS   + j*64 + d] = W_gatt[d*128 + j];    // self half of W_gatt
  }
  for (int i = t; i < 8192; i += 256){
    int j = i >> 6, d = i & 63;
    ws[OFF_WRE  + i] = W_re[d*128 + j];
    ws[OFF_WAGG + i] = W_agg[d*128 + j];
    float s = 0.f;
    for (int dp = 0; dp < 64; ++dp) s += W_gatt[d*128 + 64 + dp] * W_re[dp*128 + j];
    ws[OFF_WCOMB + i] = s;                           // (W_gatt[:,64:] @ W_re)^T
  }
  for (int i = t; i < 12288; i += 256){
    int j = i >> 6, d = i & 63;
    ws[OFF_WU + i] = W_u[d*192 + j];
  }
  if (t < 64) ws[OFF_GVEC + t] = sigmoid_fast(gate[t]);
}

// ---------------- user gather + u_att = relu(user_g @ W_tatt^T + b_tatt) ----------------
__global__ void user_prep_kernel(const int* __restrict__ uidx, const float* __restrict__ user_emb,
                                 const float* __restrict__ b_tatt, float* __restrict__ ws)
{
  int gid = blockIdx.x*256 + threadIdx.x;
  int b = gid >> 6, lane = gid & 63;
  long ui = uidx[b];
  float ugd = user_emb[ui*64 + lane];
  ws[OFF_USERG + b*64 + lane] = ugd;
  const float* WtT = ws + OFF_WTATT;
  float acc = b_tatt[lane];
  for (int j = 0; j < 64; ++j) acc += WtT[j*64 + lane] * __shfl(ugd, j);
  ws[OFF_UATT + b*64 + lane] = fmaxf(acc, 0.f);
}

// ---------------- agg_lc v2: thread = (row, k); 16 rows x 16 k per block ----------------
__global__ __launch_bounds__(256) void agg2_kernel(
  const int* __restrict__ hS, const int* __restrict__ hN, const int* __restrict__ hR,
  const int* __restrict__ pS, const int* __restrict__ pN, const int* __restrict__ pR,
  const int* __restrict__ nS, const int* __restrict__ nN, const int* __restrict__ nR,
  const float* __restrict__ entity, const float* __restrict__ relation,
  const float* __restrict__ b_gatt, const float* __restrict__ b_agg,
  float* __restrict__ ws)
{
  int tid = threadIdx.x;
  int k = tid & 15, rl = tid >> 4;          // k-lane, row-in-block
  int rbase = blockIdx.x*16;
  const int *sI, *nI, *rI; float *sO, *aO; int nb0, uhis;
  if (rbase < NH)          { sI=hS; nI=hN; rI=hR; sO=ws+OFF_SELFH;        aO=ws+OFF_HISLC;       nb0=rbase;        uhis=1; }
  else if (rbase < NH+Bb)  { sI=pS; nI=pN; rI=pR; sO=ws+OFF_SELFPN;       aO=ws+OFF_LCPN;       nb0=rbase-NH;     uhis=0; }
  else                     { sI=nS; nI=nN; rI=nR; sO=ws+OFF_SELFPN+65536; aO=ws+OFF_LCPN+65536; nb0=rbase-NH-Bb;  uhis=0; }
  int n = nb0 + rl;
  int urow = uhis ? (n >> 5) : n;

  const float* es = entity + (long)sI[n]*64;
  // ---- sc part: lane owns outputs o = k*4 .. k*4+3 of  sc = b_gatt + Wg_self@self ----
  const float* WgsT = ws + OFF_WGS;
  float4 sc4 = ld4(b_gatt + k*4);
  for (int j4 = 0; j4 < 16; ++j4){
    float4 s4 = ld4(es + 4*j4);
    float4 w0 = ld4(WgsT + (4*j4+0)*64 + k*4);
    float4 w1 = ld4(WgsT + (4*j4+1)*64 + k*4);
    float4 w2 = ld4(WgsT + (4*j4+2)*64 + k*4);
    float4 w3 = ld4(WgsT + (4*j4+3)*64 + k*4);
    sc4.x += w0.x*s4.x + w1.x*s4.y + w2.x*s4.z + w3.x*s4.w;
    sc4.y += w0.y*s4.x + w1.y*s4.y + w2.y*s4.z + w3.y*s4.w;
    sc4.z += w0.z*s4.x + w1.z*s4.y + w2.z*s4.z + w3.z*s4.w;
    sc4.w += w0.w*s4.x + w1.w*s4.y + w2.w*s4.z + w3.w*s4.w;
  }
  // store self_v chunk (lane k stores dims k*4..k*4+3)
  st4(sO + (long)n*64 + k*4, ld4(es + k*4));

  // ---- neighbor matvec: acc = Wcomb @ [nbr | rel]  (wave-uniform s_load weights) ----
  long nbI = nI[n*16 + k], rlI = rI[n*16 + k];
  const float* en = entity + nbI*64;
  const float* er = relation + rlI*64;
  float xnb[64];
  #pragma unroll
  for (int j4 = 0; j4 < 16; ++j4){
    float4 x4 = ld4(en + 4*j4);
    xnb[4*j4+0] = x4.x; xnb[4*j4+1] = x4.y; xnb[4*j4+2] = x4.z; xnb[4*j4+3] = x4.w;
  }
  float acc[64];
  #pragma unroll
  for (int d = 0; d < 64; ++d) acc[d] = 0.f;
  const float* WcT = ws + OFF_WCOMB;
  for (int j4 = 0; j4 < 16; ++j4){
    float4 x4 = ld4(en + 4*j4);
    MV4(acc, WcT + j4*256, x4);
  }
  for (int j4 = 0; j4 < 16; ++j4){
    float4 x4 = ld4(er + 4*j4);
    MV4(acc, WcT + 4096 + j4*256, x4);
  }
  // ---- logit = u_att . tanh(sc + acc)  (sc broadcast from owner lanes) ----
  int gl = (tid & 63) & 48;                 // group base lane within wave
  const float* up = ws + OFF_UATT + (long)urow*64;
  float lg = 0.f;
  #pragma unroll
  for (int j4 = 0; j4 < 16; ++j4){
    float4 u4 = ld4(up + 4*j4);
    float s0 = __shfl(sc4.x, gl + j4);
    float s1 = __shfl(sc4.y, gl + j4);
    float s2 = __shfl(sc4.z, gl + j4);
    float s3 = __shfl(sc4.w, gl + j4);
    lg += u4.x*tanh_fast(acc[4*j4+0] + s0);
    lg += u4.y*tanh_fast(acc[4*j4+1] + s1);
    lg += u4.z*tanh_fast(acc[4*j4+2] + s2);
    lg += u4.w*tanh_fast(acc[4*j4+3] + s3);
  }
  // ---- softmax over the 16 k-lanes ----
  float mx = lg;
  mx = fmaxf(mx, __shfl_xor(mx, 1)); mx = fmaxf(mx, __shfl_xor(mx, 2));
  mx = fmaxf(mx, __shfl_xor(mx, 4)); mx = fmaxf(mx, __shfl_xor(mx, 8));
  float e = __expf(lg - mx);
  float se = e;
  se += __shfl_xor(se, 1); se += __shfl_xor(se, 2);
  se += __shfl_xor(se, 4); se += __shfl_xor(se, 8);
  float att = __fdividef(e, se);
  // ---- agg: lane computes outputs o = k*4..k*4+3 of tanh(W_agg@[self|new_v]+b) ----
  const float* WaT = ws + OFF_WAGG;
  float4 a4 = ld4(b_agg + k*4);
  for (int j4 = 0; j4 < 16; ++j4){          // self half (streamed, L1-hot)
    float4 s4 = ld4(es + 4*j4);
    float4 w0 = ld4(WaT + (4*j4+0)*64 + k*4);
    float4 w1 = ld4(WaT + (4*j4+1)*64 + k*4);
    float4 w2 = ld4(WaT + (4*j4+2)*64 + k*4);
    float4 w3 = ld4(WaT + (4*j4+3)*64 + k*4);
    a4.x += w0.x*s4.x + w1.x*s4.y + w2.x*s4.z + w3.x*s4.w;
    a4.y += w0.y*s4.x + w1.y*s4.y + w2.y*s4.z + w3.y*s4.w;
    a4.z += w0.z*s4.x + w1.z*s4.y + w2.z*s4.z + w3.z*s4.w;
    a4.w += w0.w*s4.x + w1.w*s4.y + w2.w*s4.z + w3.w*s4.w;
  }
  #pragma unroll
  for (int j = 0; j < 64; ++j){             // new_v half via 16-lane butterfly
    float v = att * xnb[j];
    v += __shfl_xor(v, 1); v += __shfl_xor(v, 2);
    v += __shfl_xor(v, 4); v += __shfl_xor(v, 8);
    float4 wv = ld4(WaT + (64+j)*64 + k*4);
    a4.x += wv.x*v; a4.y += wv.y*v; a4.z += wv.z*v; a4.w += wv.w*v;
  }
  float t0 = tanh_fast(a4.x), t1 = tanh_fast(a4.y), t2 = tanh_fast(a4.z), t3 = tanh_fast(a4.w);
  float ss = t0*t0 + t1*t1 + t2*t2 + t3*t3;
  ss += __shfl_xor(ss, 1); ss += __shfl_xor(ss, 2);
  ss += __shfl_xor(ss, 4); ss += __shfl_xor(ss, 8);
  float rn = __fdividef(1.f, fmaxf(sqrtf(ss), 1e-12f));
  float4 o4; o4.x = t0*rn; o4.y = t1*rn; o4.z = t2*rn; o4.w = t3*rn;
  st4(aO + (long)n*64 + k*4, o4);
}

// ---------------- GRU v5 (gru3): block = 64 rows x 8 waves; wave w owns outputs [w*8,w*8+8) ----
// Round-6 analysis: 4-wave version was grid-bound (2176 waves = 2.1/SIMD, VGPR 204 -> 2 resident).
// v5: 8 waves/block (4352 waves), h streamed from LDS inside the non-unrolled o-loop (no hc[64]
// register array -> VGPR ~110 -> ~4 resident waves/SIMD). Interleaved LDS store of h[o] blocks
// load hoisting (alias-conservative), keeping allocation small. Epilogue stages self-rows into
// a 16 KB LDS buffer instead of a second 64-reg array. NO min-waves launch bound (round-5 lesson).
__global__ __launch_bounds__(512) void gru3_kernel(
  const int* __restrict__ hS, const int* __restrict__ hP,
  const int* __restrict__ pS, const int* __restrict__ pP,
  const int* __restrict__ nS, const int* __restrict__ nP,
  const float* __restrict__ entity,
  const float* __restrict__ W_ih, const float* __restrict__ W_hh,
  const float* __restrict__ b_ih, const float* __restrict__ b_hh,
  const float* __restrict__ W_agg, const float* __restrict__ b_agg,
  float* __restrict__ ws)
{
  __shared__ float hb[2][64][64];           // [buf][dim][row] double-buffered h (32 KB)
  __shared__ float xb[64][64];              // [dim][row] staging for epilogue self rows (16 KB)
  int tid = threadIdx.x;
  int w = __builtin_amdgcn_readfirstlane(tid >> 6);   // wave id 0..7 (uniform)
  int lane = tid & 63;                                // lane = row
  int rbase = blockIdx.x*64;
  const int *sIv, *pIv; float* aO; int nb0;
  if (rbase < NH)          { sIv=hS; pIv=hP; aO=ws+OFF_HISGB;        nb0=rbase; }
  else if (rbase < NH+Bb)  { sIv=pS; pIv=pP; aO=ws+OFF_GBPN;        nb0=rbase-NH; }
  else                     { sIv=nS; pIv=nP; aO=ws+OFF_GBPN+65536;  nb0=rbase-NH-Bb; }
  int n = nb0 + lane;
  int o0 = w*8;

  for (int i = tid; i < 8192; i += 512) ((float*)hb)[i] = 0.f;   // zero both h buffers
  __syncthreads();

  for (int t = 0; t < 8; ++t){
    int pt = pIv[n*8 + t];
    const float* ex = entity + (long)pt*64;
    float x[64];
    #pragma unroll
    for (int j4 = 0; j4 < 16; ++j4){
      float4 v = ld4(ex + 4*j4);
      x[4*j4] = v.x; x[4*j4+1] = v.y; x[4*j4+2] = v.z; x[4*j4+3] = v.w;
    }
    int cur = t & 1, nxt = cur ^ 1;
    #pragma unroll 1
    for (int i = 0; i < 8; ++i){
      int o = o0 + i;
      float air = b_ih[o], aiz = b_ih[64+o], ain = b_ih[128+o];
      float ahr = b_hh[o], ahz = b_hh[64+o], ahn = b_hh[128+o];
      const float* wi0 = W_ih + o*64;  const float* wi1 = W_ih + (64+o)*64;  const float* wi2 = W_ih + (128+o)*64;
      const float* wh0 = W_hh + o*64;  const float* wh1 = W_hh + (64+o)*64;  const float* wh2 = W_hh + (128+o)*64;
      #pragma unroll
      for (int j = 0; j < 64; ++j){
        float hj = hb[cur][j][lane];           // LDS stream, not hoisted (aliases store below)
        air += wi0[j]*x[j]; aiz += wi1[j]*x[j]; ain += wi2[j]*x[j];
        ahr += wh0[j]*hj;  ahz += wh1[j]*hj;  ahn += wh2[j]*hj;
      }
      float r  = sigmoid_fast(air + ahr);
      float z  = sigmoid_fast(aiz + ahz);
      float nn = tanh_fast(ain + r*ahn);
      float hprev = hb[cur][o][lane];
      hb[nxt][o][lane] = (1.f - z)*nn + z*hprev;
    }
    __syncthreads();
  }
  // final h in hb[0]. Stage self rows into xb[dim][row] (coalesced per 8-thread row groups).
  {
    int rrow = tid & 63, chunk = tid >> 6;   // 8 chunks x 8 dims
    const float* es = entity + (long)sIv[nb0 + rrow]*64 + chunk*8;
    float4 aa = ld4(es), bb2 = ld4(es + 4);
    xb[chunk*8+0][rrow] = aa.x;  xb[chunk*8+1][rrow] = aa.y;
    xb[chunk*8+2][rrow] = aa.z;  xb[chunk*8+3][rrow] = aa.w;
    xb[chunk*8+4][rrow] = bb2.x; xb[chunk*8+5][rrow] = bb2.y;
    xb[chunk*8+6][rrow] = bb2.z; xb[chunk*8+7][rrow] = bb2.w;
  }
  __syncthreads();
  // agg = normalize(tanh(W_agg@[self|hT]+b_agg)); result transposed into hb[1]
  #pragma unroll 1
  for (int i = 0; i < 8; ++i){
    int o = o0 + i;
    float a = b_agg[o];
    const float* wr = W_agg + (long)o*128;
    #pragma unroll
    for (int j = 0; j < 64; ++j) a += wr[j]*xb[j][lane];
    #pragma unroll
    for (int j = 0; j < 64; ++j) a += wr[64+j]*hb[0][j][lane];
    hb[1][o][lane] = tanh_fast(a);
  }
  __syncthreads();
  // normalize + coalesced store: thread (q = tid&7 dims-chunk, r = tid>>3 row)
  int q = tid & 7, r = tid >> 3;
  float vv[8];
  float ss = 0.f;
  #pragma unroll
  for (int jj = 0; jj < 8; ++jj){ float v = hb[1][q*8+jj][r]; vv[jj] = v; ss += v*v; }
  ss += __shfl_xor(ss, 1); ss += __shfl_xor(ss, 2); ss += __shfl_xor(ss, 4);
  float rn = __fdividef(1.f, fmaxf(sqrtf(ss), 1e-12f));
  int n2 = nb0 + r;
  #pragma unroll
  for (int jj4 = 0; jj4 < 2; ++jj4){
    float4 o4; o4.x = vv[4*jj4]*rn; o4.y = vv[4*jj4+1]*rn; o4.z = vv[4*jj4+2]*rn; o4.w = vv[4*jj4+3]*rn;
    st4(aO + (long)n2*64 + q*8 + 4*jj4, o4);
  }
}

// ---------------- KG v2: thread = (r, branch); store squared distances ----------------
__global__ __launch_bounds__(256) void kg2_kernel(
  const int* __restrict__ kh, const int* __restrict__ kr,
  const int* __restrict__ kt, const int* __restrict__ ktn,
  const float* __restrict__ entity, const float* __restrict__ relation,
  float* __restrict__ ws)
{
  int tid = threadIdx.x;
  int br = blockIdx.x >> 8;
  int r  = (blockIdx.x & 255)*256 + tid;
  const int* tailI = br ? ktn : kt;
  const float* WreT = ws + OFF_WRE;
  const float* er = relation + (long)kr[r]*64;
  const float* et = entity + (long)tailI[r]*64;
  float acc[64];
  #pragma unroll
  for (int d = 0; d < 64; ++d) acc[d] = 0.f;
  for (int j4 = 0; j4 < 16; ++j4){
    float4 x4 = ld4(et + 4*j4);
    MV4(acc, WreT + j4*256, x4);
  }
  for (int j4 = 0; j4 < 16; ++j4){
    float4 x4 = ld4(er + 4*j4);
    MV4(acc, WreT + 4096 + j4*256, x4);
  }
  const float* eh = entity + (long)kh[r]*64;
  float s = 0.f;
  #pragma unroll
  for (int j4 = 0; j4 < 16; ++j4){
    float4 h4 = ld4(eh + 4*j4);
    float d0 = h4.x - acc[4*j4+0], d1 = h4.y - acc[4*j4+1];
    float d2 = h4.z - acc[4*j4+2], d3 = h4.w - acc[4*j4+3];
    s += d0*d0 + d1*d1 + d2*d2 + d3*d3;
  }
  ws[OFF_KGS + br*65536 + r] = s;
}

__global__ void kg_reduce_kernel(float* __restrict__ ws)
{
  int r = blockIdx.x*256 + threadIdx.x;
  float s  = ws[OFF_KGS + r];
  float sn = ws[OFF_KGS + 65536 + r];
  float dif = sn - s;
  float ls = fminf(dif, 0.f) - __logf(1.f + __expf(-fabsf(dif)));
  #pragma unroll
  for (int m2 = 1; m2 < 64; m2 <<= 1) ls += __shfl_xor(ls, m2);
  if ((threadIdx.x & 63) == 0) atomicAdd(ws + OFF_KGSUM, ls);
}

// ---------------- rs_att: one wave per (b, branch) ----------------
__global__ void rsatt_kernel(const float* __restrict__ W_iatt, const float* __restrict__ b_iatt,
                             float* __restrict__ ws)
{
  int gid = blockIdx.x*256 + threadIdx.x;
  int gw = gid >> 6, lane = gid & 63;
  int b = gw >> 1, br = gw & 1;
  const float* selfB = ws + OFF_SELFPN + br*65536 + b*64;
  const float* lcB   = ws + OFF_LCPN   + br*65536 + b*64;
  const float* gbB   = ws + OFF_GBPN   + br*65536 + b*64;
  const float* gvec  = ws + OFF_GVEC;
  const float* selfH = ws + OFF_SELFH;
  const float* hisLC = ws + OFF_HISLC;
  const float* hisGB = ws + OFF_HISGB;

  float gd = gvec[lane];
  float sv = selfB[lane], lcv = lcB[lane], gbv = gbB[lane];
  float gated = gd*lcv + (1.f - gd)*gbv;
  float part = W_iatt[128+lane]*sv + W_iatt[192+lane]*gated;   // item half of logit dot
  #pragma unroll
  for (int m2 = 1; m2 < 64; m2 <<= 1) part += __shfl_xor(part, m2);
  float itemdot = part + b_iatt[0];

  int m = lane & 31, half = lane >> 5;
  long nrow = (long)(b*32 + m)*64;
  float sh = 0.f;
  if (half == 0){
    for (int j4 = 0; j4 < 16; ++j4){
      float4 h4 = ld4(selfH + nrow + 4*j4);
      float4 w4 = ld4(W_iatt + 4*j4);
      sh += w4.x*h4.x + w4.y*h4.y + w4.z*h4.z + w4.w*h4.w;
    }
  } else {
    for (int j4 = 0; j4 < 16; ++j4){
      float4 l4 = ld4(hisLC + nrow + 4*j4);
      float4 g4 = ld4(hisGB + nrow + 4*j4);
      float4 gg = ld4(gvec + 4*j4);
      float4 w4 = ld4(W_iatt + 64 + 4*j4);
      sh += w4.x*(gg.x*l4.x + (1.f-gg.x)*g4.x);
      sh += w4.y*(gg.y*l4.y + (1.f-gg.y)*g4.y);
      sh += w4.z*(gg.z*l4.z + (1.f-gg.z)*g4.z);
      sh += w4.w*(gg.w*l4.w + (1.f-gg.w)*g4.w);
    }
  }
  sh += __shfl_xor(sh, 32);
  float logit = tanh_fast(sh + itemdot);
  float mxv = logit;
  #pragma unroll
  for (int m2 = 1; m2 < 32; m2 <<= 1) mxv = fmaxf(mxv, __shfl_xor(mxv, m2));
  float e = __expf(logit - mxv);
  float se = e;
  #pragma unroll
  for (int m2 = 1; m2 < 32; m2 <<= 1) se += __shfl_xor(se, m2);
  float att = __fdividef(e, se);

  // u_lc[d] (lane=d over 2 halves)
  float u1 = 0.f, u2 = 0.f;
  for (int mm = 0; mm < 32; ++mm){
    float a = __shfl(att, mm);
    long nr = (long)(b*32 + mm)*64;
    float x1 = selfH[nr + lane];
    float x2 = gd*hisLC[nr + lane] + (1.f - gd)*hisGB[nr + lane];
    u1 += a*x1; u2 += a*x2;
  }
  float* upo = ws + OFF_ULCPN + (long)(br*1024 + b)*128;
  upo[lane] = u1; upo[64 + lane] = u2;
}

// ---------------- u-MLP + score: one wave per (b, branch) ----------------
__global__ void umlp_kernel(const float* __restrict__ b_u, float* __restrict__ ws, float* __restrict__ out)
{
  int gid = blockIdx.x*256 + threadIdx.x;
  int gw = gid >> 6, lane = gid & 63;
  int b = gw >> 1, br = gw & 1;
  const float* WuT = ws + OFF_WU;
  const float* ug  = ws + OFF_USERG + b*64;
  const float* ul  = ws + OFF_ULCPN + (long)(br*1024 + b)*128;
  float acc = b_u[lane];
  for (int j = 0; j < 64; ++j)  acc += WuT[j*64 + lane] * ug[j];
  for (int j = 0; j < 128; ++j) acc += WuT[(64 + j)*64 + lane] * ul[j];
  float uo = fmaxf(acc, 0.f);
  float ssv = uo*uo;
  #pragma unroll
  for (int m2 = 1; m2 < 64; m2 <<= 1) ssv += __shfl_xor(ssv, m2);
  float rn = __fdividef(1.f, fmaxf(sqrtf(ssv), 1e-12f));
  float nuo = uo*rn;
  const float* selfB = ws + OFF_SELFPN + br*65536 + b*64;
  const float* lcB   = ws + OFF_LCPN   + br*65536 + b*64;
  const float* gbB   = ws + OFF_GBPN   + br*65536 + b*64;
  float gd = ws[OFF_GVEC + lane];
  float gated = gd*lcB[lane] + (1.f - gd)*gbB[lane];
  float p = ug[lane]*selfB[lane] + nuo*gated;
  #pragma unroll
  for (int m2 = 1; m2 < 64; m2 <<= 1) p += __shfl_xor(p, m2);
  if (lane == 0) out[br*1024 + b] = p;
}

// ---------------- final loss ----------------
__global__ void loss_kernel(const float* __restrict__ ws, float* __restrict__ out)
{
  __shared__ float red[16];
  int t = threadIdx.x;
  float ps = out[t], ns_ = out[1024 + t];
  float dif = ps - ns_;
  float v = fminf(dif, 0.f) - __logf(1.f + __expf(-fabsf(dif)));
  #pragma unroll
  for (int m2 = 1; m2 < 64; m2 <<= 1) v += __shfl_xor(v, m2);
  if ((t & 63) == 0) red[t >> 6] = v;
  __syncthreads();
  if (t == 0){
    float s = 0.f;
    for (int i = 0; i < 16; ++i) s += red[i];
    float rs = -s * (1.f/1024.f);
    float kg = -ws[OFF_KGSUM] * (1.f/65536.f);
    out[2048] = rs + kg;
  }
}

extern "C" void kernel_launch(void* const* d_in, const int* in_sizes, int n_in,
                              void* d_out, int out_size, void* d_ws, size_t ws_size,
                              hipStream_t stream)
{
  const int* user_indices = (const int*)d_in[0];
  const int* ent_his_self = (const int*)d_in[1];
  const int* ent_his_nbr  = (const int*)d_in[2];
  const int* rel_his      = (const int*)d_in[3];
  const int* ent_pos_self = (const int*)d_in[4];
  const int* ent_pos_nbr  = (const int*)d_in[5];
  const int* rel_pos      = (const int*)d_in[6];
  const int* ent_neg_self = (const int*)d_in[7];
  const int* ent_neg_nbr  = (const int*)d_in[8];
  const int* rel_neg      = (const int*)d_in[9];
  const int* gb_his_self  = (const int*)d_in[10];
  const int* gb_his_path  = (const int*)d_in[11];
  const int* gb_pos_self  = (const int*)d_in[12];
  const int* gb_pos_path  = (const int*)d_in[13];
  const int* gb_neg_self  = (const int*)d_in[14];
  const int* gb_neg_path  = (const int*)d_in[15];
  const int* kg_head      = (const int*)d_in[16];
  const int* kg_rel       = (const int*)d_in[17];
  const int* kg_tail      = (const int*)d_in[18];
  const int* kg_tail_neg  = (const int*)d_in[19];
  const float* entity_emb   = (const float*)d_in[20];
  const float* relation_emb = (const float*)d_in[21];
  const float* user_emb     = (const float*)d_in[22];
  const float* gate         = (const float*)d_in[23];
  const float* W_u_mlp      = (const float*)d_in[24];
  const float* b_u_mlp      = (const float*)d_in[25];
  const float* W_re         = (const float*)d_in[26];
  const float* W_agg        = (const float*)d_in[27];
  const float* b_agg        = (const float*)d_in[28];
  const float* W_gatt       = (const float*)d_in[29];
  const float* b_gatt       = (const float*)d_in[30];
  const float* W_iatt       = (const float*)d_in[31];
  const float* b_iatt       = (const float*)d_in[32];
  const float* W_tatt       = (const float*)d_in[33];
  const float* b_tatt       = (const float*)d_in[34];
  const float* W_ih         = (const float*)d_in[35];
  const float* W_hh         = (const float*)d_in[36];
  const float* b_ih         = (const float*)d_in[37];
  const float* b_hh         = (const float*)d_in[38];
  float* ws  = (float*)d_ws;
  float* out = (float*)d_out;

  (void)hipMemsetAsync(ws + OFF_KGSUM, 0, sizeof(float), stream);
  prep_kernel<<<1, 256, 0, stream>>>(W_tatt, W_gatt, W_re, W_agg, W_u_mlp, gate, ws);
  user_prep_kernel<<<256, 256, 0, stream>>>(user_indices, user_emb, b_tatt, ws);
  agg2_kernel<<<ROWS/16, 256, 0, stream>>>(
      ent_his_self, ent_his_nbr, rel_his,
      ent_pos_self, ent_pos_nbr, rel_pos,
      ent_neg_self, ent_neg_nbr, rel_neg,
      entity_emb, relation_emb, b_gatt, b_agg, ws);
  gru3_kernel<<<ROWS/64, 512, 0, stream>>>(
      gb_his_self, gb_his_path, gb_pos_self, gb_pos_path,
      gb_neg_self, gb_neg_path, entity_emb,
      W_ih, W_hh, b_ih, b_hh, W_agg, b_agg, ws);
  kg2_kernel<<<512, 256, 0, stream>>>(kg_head, kg_rel, kg_tail, kg_tail_neg,
                                      entity_emb, relation_emb, ws);
  kg_reduce_kernel<<<256, 256, 0, stream>>>(ws);
  rsatt_kernel<<<512, 256, 0, stream>>>(W_iatt, b_iatt, ws);
  umlp_kernel<<<512, 256, 0, stream>>>(b_u_mlp, ws, out);
  loss_kernel<<<1, 1024, 0, stream>>>(ws, out);
}